// Round 1
// baseline (3000.765 us; speedup 1.0000x reference)
//
#include <hip/hip_runtime.h>
#include <hip/hip_bf16.h>

// ---------------------------------------------------------------------------
// AgentAwareAttention (MI355X / gfx950) — Round 1: correct f32 baseline
//   B=4, N=2009, DIM=512, H=8, Dh=64. Outputs: out [4,2009,512] ++ attn [4,8,2009,2009]
// Pipeline:
//   1) gemm_f32: proj1 = x @ w_qkv        [8036 x 1536]  (q|k|v)
//   2) gemm_f32: proj2 = x @ w_qk_self    [8036 x 1024]  (qs|ks)
//   3) attn_fused: per (b,h,16-row tile): QK^T -> exp (LDS) -> diag-block
//      self-attn fix-up -> row sums -> write normalized attn + O = attn@V
//   4) gemm_f32: out = O @ w_out + b_out  [8036 x 512]
// ---------------------------------------------------------------------------

#define N_TOK   2009
#define BATCH_  4
#define HEADS_  8
#define MROWS   8036          // BATCH_*N_TOK
#define EPITCH  2016          // padded row length for e[] in LDS
#define TM      16            // rows per attention block
#define SCALE_  0.125f

static inline int cdiv(int a, int b) { return (a + b - 1) / b; }

__device__ __forceinline__ float4 ld4(const float* p) {
    return *reinterpret_cast<const float4*>(p);
}

// ---------------------------------------------------------------------------
// Tiled f32 GEMM: C[M,Nc] = A[M,K] * B[K,Nc] (+bias).  Nc % 64 == 0, K % 32 == 0.
// BM=BN=64, BK=32, 256 threads, 4x4 outputs/thread.
// ---------------------------------------------------------------------------
#define TILE_M 64
#define TILE_N 64
#define TILE_K 32
#define APAD   68

__global__ __launch_bounds__(256)
void gemm_f32(const float* __restrict__ A, const float* __restrict__ B,
              float* __restrict__ C, const float* __restrict__ bias,
              int M, int Nc, int K)
{
    __shared__ float As[TILE_K * APAD];    // As[k*APAD + m]  (transposed on store)
    __shared__ float Bs[TILE_K * TILE_N];  // Bs[k*64 + n]

    const int tid = threadIdx.x;
    const int m0  = blockIdx.x * TILE_M;
    const int n0  = blockIdx.y * TILE_N;
    const int tx  = tid & 15;   // n quad
    const int ty  = tid >> 4;   // m quad

    float acc[4][4] = {};

    for (int k0 = 0; k0 < K; k0 += TILE_K) {
        // --- load A tile (64 rows x 32 k) as 512 float4, transpose into As[k][m]
#pragma unroll
        for (int i = 0; i < 2; ++i) {
            int f  = tid * 2 + i;
            int m  = f >> 3;
            int kc = f & 7;
            float4 v = make_float4(0.f, 0.f, 0.f, 0.f);
            int gm = m0 + m;
            if (gm < M)
                v = ld4(A + (size_t)gm * K + k0 + kc * 4);
            As[(kc * 4 + 0) * APAD + m] = v.x;
            As[(kc * 4 + 1) * APAD + m] = v.y;
            As[(kc * 4 + 2) * APAD + m] = v.z;
            As[(kc * 4 + 3) * APAD + m] = v.w;
        }
        // --- load B tile (32 k x 64 n) as 512 float4, direct
#pragma unroll
        for (int i = 0; i < 2; ++i) {
            int f  = tid * 2 + i;
            int kk = f >> 4;
            int nc = f & 15;
            float4 v = ld4(B + (size_t)(k0 + kk) * Nc + n0 + nc * 4);
            *reinterpret_cast<float4*>(&Bs[kk * TILE_N + nc * 4]) = v;
        }
        __syncthreads();

#pragma unroll
        for (int k = 0; k < TILE_K; ++k) {
            float4 a = *reinterpret_cast<const float4*>(&As[k * APAD + ty * 4]);
            float4 b = *reinterpret_cast<const float4*>(&Bs[k * TILE_N + tx * 4]);
            acc[0][0] += a.x * b.x; acc[0][1] += a.x * b.y; acc[0][2] += a.x * b.z; acc[0][3] += a.x * b.w;
            acc[1][0] += a.y * b.x; acc[1][1] += a.y * b.y; acc[1][2] += a.y * b.z; acc[1][3] += a.y * b.w;
            acc[2][0] += a.z * b.x; acc[2][1] += a.z * b.y; acc[2][2] += a.z * b.z; acc[2][3] += a.z * b.w;
            acc[3][0] += a.w * b.x; acc[3][1] += a.w * b.y; acc[3][2] += a.w * b.z; acc[3][3] += a.w * b.w;
        }
        __syncthreads();
    }

    float4 bv = make_float4(0.f, 0.f, 0.f, 0.f);
    if (bias) bv = ld4(bias + n0 + tx * 4);

#pragma unroll
    for (int i = 0; i < 4; ++i) {
        int gm = m0 + ty * 4 + i;
        if (gm < M) {
            float4 o;
            o.x = acc[i][0] + bv.x;
            o.y = acc[i][1] + bv.y;
            o.z = acc[i][2] + bv.z;
            o.w = acc[i][3] + bv.w;
            *reinterpret_cast<float4*>(C + (size_t)gm * Nc + n0 + tx * 4) = o;
        }
    }
}

// ---------------------------------------------------------------------------
// Fused attention. Block = 256 threads handles (b, h, 16 rows).
// proj1 row layout: [q(512) | k(512) | v(512)], proj2: [qs(512) | ks(512)].
// LDS: e[TM][EPITCH] (exp of logits), q[TM][64], qs[TM][64], rinv[TM].
// ---------------------------------------------------------------------------
__global__ __launch_bounds__(256)
void attn_fused(const float* __restrict__ proj1, const float* __restrict__ proj2,
                float* __restrict__ attn, float* __restrict__ Obuf)
{
    extern __shared__ float smem[];
    float* eS   = smem;                    // TM * EPITCH
    float* qS   = eS + TM * EPITCH;        // TM * 64
    float* qsS  = qS + TM * 64;            // TM * 64
    float* rinv = qsS + TM * 64;           // TM

    const int tid  = threadIdx.x;
    const int row0 = blockIdx.x * TM;
    const int h    = blockIdx.y;
    const int b    = blockIdx.z;
    const size_t bN = (size_t)b * N_TOK;

    // ---- phase 0: load q, qs tiles (16 rows x 64) ----
    {
        int r  = tid >> 4;
        int c  = tid & 15;
        int gr = row0 + r;
        float4 qv  = make_float4(0.f, 0.f, 0.f, 0.f);
        float4 qsv = make_float4(0.f, 0.f, 0.f, 0.f);
        if (gr < N_TOK) {
            qv  = ld4(proj1 + (bN + gr) * 1536 + h * 64 + c * 4);
            qsv = ld4(proj2 + (bN + gr) * 1024 + h * 64 + c * 4);
        }
        *reinterpret_cast<float4*>(&qS [r * 64 + c * 4]) = qv;
        *reinterpret_cast<float4*>(&qsS[r * 64 + c * 4]) = qsv;
    }
    __syncthreads();

    // ---- phase 1: e[r][j] = exp(SCALE * q_r . k_j), 2 cols per thread/iter ----
    for (int j0 = 0; j0 < N_TOK; j0 += 512) {
        int j1 = j0 + tid;
        int j2 = j1 + 256;
        bool v1 = (j1 < N_TOK), v2 = (j2 < N_TOK);
        const float* kp1 = proj1 + (bN + (v1 ? j1 : 0)) * 1536 + 512 + h * 64;
        const float* kp2 = proj1 + (bN + (v2 ? j2 : 0)) * 1536 + 512 + h * 64;
        float acc1[TM], acc2[TM];
#pragma unroll
        for (int r = 0; r < TM; ++r) { acc1[r] = 0.f; acc2[r] = 0.f; }
#pragma unroll 4
        for (int c = 0; c < 16; ++c) {
            float4 k1 = v1 ? ld4(kp1 + c * 4) : make_float4(0.f, 0.f, 0.f, 0.f);
            float4 k2 = v2 ? ld4(kp2 + c * 4) : make_float4(0.f, 0.f, 0.f, 0.f);
#pragma unroll
            for (int r = 0; r < TM; ++r) {
                float4 qv = *reinterpret_cast<const float4*>(&qS[r * 64 + c * 4]);
                acc1[r] += qv.x * k1.x + qv.y * k1.y + qv.z * k1.z + qv.w * k1.w;
                acc2[r] += qv.x * k2.x + qv.y * k2.y + qv.z * k2.z + qv.w * k2.w;
            }
        }
#pragma unroll
        for (int r = 0; r < TM; ++r) {
            if (v1) eS[r * EPITCH + j1] = __expf(acc1[r] * SCALE_);
            if (v2) eS[r * EPITCH + j2] = __expf(acc2[r] * SCALE_);
        }
    }
    __syncthreads();

    // ---- phase 2: diagonal-block self-attention fix-up (10 cols per agent row) ----
    if (tid < TM * 10) {
        int r = tid / 10;
        int c = tid % 10;
        int i = row0 + r;
        if (i < 2000) {
            int j = (i / 10) * 10 + c;
            const float* kp = proj2 + (bN + j) * 1024 + 512 + h * 64;
            float acc = 0.f;
#pragma unroll 4
            for (int c4 = 0; c4 < 16; ++c4) {
                float4 kv = ld4(kp + c4 * 4);
                float4 qv = ld4(&qsS[r * 64 + c4 * 4]);
                acc += qv.x * kv.x + qv.y * kv.y + qv.z * kv.z + qv.w * kv.w;
            }
            eS[r * EPITCH + j] = __expf(acc * SCALE_);
        }
    }
    __syncthreads();

    // ---- phase 3: row sums -> rinv ----
    {
        int r = tid >> 4;
        int l = tid & 15;
        float s = 0.f;
        for (int j = l; j < N_TOK; j += 16) s += eS[r * EPITCH + j];
#pragma unroll
        for (int m = 8; m >= 1; m >>= 1) s += __shfl_xor(s, m, 16);
        if (l == 0) rinv[r] = 1.0f / s;
    }
    __syncthreads();

    float ri[TM];
#pragma unroll
    for (int r = 0; r < TM; ++r) ri[r] = rinv[r];

    // ---- phase 4: write normalized attn rows (coalesced) ----
    {
        float* arow = attn + ((size_t)((b * HEADS_ + h) * N_TOK + row0)) * N_TOK;
#pragma unroll 1
        for (int j = tid; j < N_TOK; j += 256) {
#pragma unroll
            for (int r = 0; r < TM; ++r) {
                if (row0 + r < N_TOK)
                    arow[(size_t)r * N_TOK + j] = eS[r * EPITCH + j] * ri[r];
            }
        }
    }

    // ---- phase 5: O[r][dg*4..+3] = (sum_j e[r][j] * V[j]) * rinv[r] ----
    {
        const int r  = tid >> 4;
        const int dg = tid & 15;
        const float* vcol = proj1 + bN * 1536 + 1024 + h * 64 + dg * 4;
        const float* erow = &eS[r * EPITCH];
        float4 s0 = make_float4(0.f,0.f,0.f,0.f), s1 = s0, s2 = s0, s3 = s0;
        int j = 0;
        for (; j + 8 <= N_TOK; j += 8) {
            float e0 = erow[j+0], e1 = erow[j+1], e2 = erow[j+2], e3 = erow[j+3];
            float e4 = erow[j+4], e5 = erow[j+5], e6 = erow[j+6], e7 = erow[j+7];
            float4 v0 = ld4(vcol + (size_t)(j+0) * 1536);
            float4 v1 = ld4(vcol + (size_t)(j+1) * 1536);
            float4 v2 = ld4(vcol + (size_t)(j+2) * 1536);
            float4 v3 = ld4(vcol + (size_t)(j+3) * 1536);
            float4 v4 = ld4(vcol + (size_t)(j+4) * 1536);
            float4 v5 = ld4(vcol + (size_t)(j+5) * 1536);
            float4 v6 = ld4(vcol + (size_t)(j+6) * 1536);
            float4 v7 = ld4(vcol + (size_t)(j+7) * 1536);
            s0.x += e0*v0.x; s0.y += e0*v0.y; s0.z += e0*v0.z; s0.w += e0*v0.w;
            s1.x += e1*v1.x; s1.y += e1*v1.y; s1.z += e1*v1.z; s1.w += e1*v1.w;
            s2.x += e2*v2.x; s2.y += e2*v2.y; s2.z += e2*v2.z; s2.w += e2*v2.w;
            s3.x += e3*v3.x; s3.y += e3*v3.y; s3.z += e3*v3.z; s3.w += e3*v3.w;
            s0.x += e4*v4.x; s0.y += e4*v4.y; s0.z += e4*v4.z; s0.w += e4*v4.w;
            s1.x += e5*v5.x; s1.y += e5*v5.y; s1.z += e5*v5.z; s1.w += e5*v5.w;
            s2.x += e6*v6.x; s2.y += e6*v6.y; s2.z += e6*v6.z; s2.w += e6*v6.w;
            s3.x += e7*v7.x; s3.y += e7*v7.y; s3.z += e7*v7.z; s3.w += e7*v7.w;
        }
        for (; j < N_TOK; ++j) {
            float e0 = erow[j];
            float4 v0 = ld4(vcol + (size_t)j * 1536);
            s0.x += e0*v0.x; s0.y += e0*v0.y; s0.z += e0*v0.z; s0.w += e0*v0.w;
        }
        int gr = row0 + r;
        if (gr < N_TOK) {
            float sc = ri[0];
            // need rinv[r] for THIS thread's row; ri[] is register array with
            // compile-time indices only -> read from LDS directly (broadcast).
            sc = rinv[r];
            float4 o;
            o.x = (s0.x + s1.x + s2.x + s3.x) * sc;
            o.y = (s0.y + s1.y + s2.y + s3.y) * sc;
            o.z = (s0.z + s1.z + s2.z + s3.z) * sc;
            o.w = (s0.w + s1.w + s2.w + s3.w) * sc;
            *reinterpret_cast<float4*>(Obuf + (bN + gr) * 512 + h * 64 + dg * 4) = o;
        }
    }
}

// ---------------------------------------------------------------------------
extern "C" void kernel_launch(void* const* d_in, const int* in_sizes, int n_in,
                              void* d_out, int out_size, void* d_ws, size_t ws_size,
                              hipStream_t stream)
{
    const float* x         = (const float*)d_in[0];   // [4,2009,512]
    const float* w_qkv     = (const float*)d_in[1];   // [512,1536]
    const float* w_qk_self = (const float*)d_in[2];   // [512,1024]
    const float* w_out     = (const float*)d_in[3];   // [512,512]
    const float* b_out     = (const float*)d_in[4];   // [512]

    float* out  = (float*)d_out;                               // [8036,512]
    float* attn = out + (size_t)MROWS * 512;                   // [4,8,2009,2009]

    float* proj1 = (float*)d_ws;                               // [8036,1536]
    float* proj2 = proj1 + (size_t)MROWS * 1536;               // [8036,1024]
    float* Obuf  = proj2 + (size_t)MROWS * 1024;               // [8036,512]
    // ws usage: 8036*(1536+1024+512)*4 = 98,746,368 bytes

    const int smem_bytes = (TM * EPITCH + 2 * TM * 64 + TM) * sizeof(float); // 137,280 B
    hipFuncSetAttribute((const void*)attn_fused,
                        hipFuncAttributeMaxDynamicSharedMemorySize, smem_bytes);

    const int mt = cdiv(MROWS, TILE_M);   // 126

    dim3 g1(mt, 1536 / TILE_N);
    gemm_f32<<<g1, 256, 0, stream>>>(x, w_qkv, proj1, nullptr, MROWS, 1536, 512);

    dim3 g2(mt, 1024 / TILE_N);
    gemm_f32<<<g2, 256, 0, stream>>>(x, w_qk_self, proj2, nullptr, MROWS, 1024, 512);

    dim3 ga(cdiv(N_TOK, TM), HEADS_, BATCH_);
    attn_fused<<<ga, 256, smem_bytes, stream>>>(proj1, proj2, attn, Obuf);

    dim3 g3(mt, 512 / TILE_N);
    gemm_f32<<<g3, 256, 0, stream>>>(Obuf, w_out, out, b_out, MROWS, 512, 512);
}

// Round 2
// 1261.860 us; speedup vs baseline: 2.3780x; 2.3780x over previous
//
#include <hip/hip_runtime.h>
#include <hip/hip_bf16.h>

// ---------------------------------------------------------------------------
// AgentAwareAttention (MI355X / gfx950) — Round 2: MFMA attention
//   B=4, N=2009, DIM=512, H=8, Dh=64. Outputs: out [4,2009,512] ++ attn [4,8,2009,2009]
// Pipeline:
//   1) gemm_f32: proj1 = x @ w_qkv        [8036 x 1536]  (q|k|v)
//   2) gemm_f32: proj2 = x @ w_qk_self    [8036 x 1024]  (qs|ks)
//   3) attn_ek (MFMA): per (b,h,64 rows): S=QK^T (split-bf16, 3-mfma),
//      e=exp(S*scale) -> attn buffer (f32, unnormalized), diag-block self
//      override (f32 VALU), rowsums -> rinv (ws), O = e@V (bf16 mfma) -> Obuf
//   4) attn_scale: attn *= rinv[row] in place
//   5) gemm_f32: out = Obuf @ w_out + b_out
// ---------------------------------------------------------------------------

#define N_TOK   2009
#define BATCH_  4
#define HEADS_  8
#define MROWS   8036          // BATCH_*N_TOK
#define SCALE_  0.125f

typedef __attribute__((ext_vector_type(8)))  short sh8;     // 8 bf16 (4 VGPR)
typedef __attribute__((ext_vector_type(16))) float f32x16;  // mfma 32x32 acc

static inline int cdiv(int a, int b) { return (a + b - 1) / b; }

__device__ __forceinline__ float4 ld4(const float* p) {
    return *reinterpret_cast<const float4*>(p);
}
__device__ __forceinline__ unsigned short f2bf(float f) {
    __hip_bfloat16 h = __float2bfloat16(f);
    return *reinterpret_cast<unsigned short*>(&h);
}
__device__ __forceinline__ float bf2f(unsigned short u) {
    return __uint_as_float(((unsigned)u) << 16);
}
// 8 floats -> bf16 hi + bf16 lo (split for 2^-16 precision)
__device__ __forceinline__ void cvt8(const float4& a, const float4& b, sh8& hi, sh8& lo) {
    float f[8] = {a.x, a.y, a.z, a.w, b.x, b.y, b.z, b.w};
#pragma unroll
    for (int i = 0; i < 8; ++i) {
        unsigned short h = f2bf(f[i]);
        hi[i] = (short)h;
        lo[i] = (short)f2bf(f[i] - bf2f(h));
    }
}
__device__ __forceinline__ void cvt8p(const float4& a, const float4& b, sh8& hi) {
#pragma unroll
    for (int i = 0; i < 4; ++i) { hi[i] = (short)f2bf((&a.x)[i]); hi[4+i] = (short)f2bf((&b.x)[i]); }
}

// ---------------------------------------------------------------------------
// Tiled f32 GEMM (unchanged from round 1): C[M,Nc] = A[M,K]*B[K,Nc] (+bias)
// ---------------------------------------------------------------------------
#define TILE_M 64
#define TILE_N 64
#define TILE_K 32
#define APAD   68

__global__ __launch_bounds__(256)
void gemm_f32(const float* __restrict__ A, const float* __restrict__ B,
              float* __restrict__ C, const float* __restrict__ bias,
              int M, int Nc, int K)
{
    __shared__ float As[TILE_K * APAD];
    __shared__ float Bs[TILE_K * TILE_N];

    const int tid = threadIdx.x;
    const int m0  = blockIdx.x * TILE_M;
    const int n0  = blockIdx.y * TILE_N;
    const int tx  = tid & 15;
    const int ty  = tid >> 4;

    float acc[4][4] = {};

    for (int k0 = 0; k0 < K; k0 += TILE_K) {
#pragma unroll
        for (int i = 0; i < 2; ++i) {
            int f  = tid * 2 + i;
            int m  = f >> 3;
            int kc = f & 7;
            float4 v = make_float4(0.f, 0.f, 0.f, 0.f);
            int gm = m0 + m;
            if (gm < M) v = ld4(A + (size_t)gm * K + k0 + kc * 4);
            As[(kc * 4 + 0) * APAD + m] = v.x;
            As[(kc * 4 + 1) * APAD + m] = v.y;
            As[(kc * 4 + 2) * APAD + m] = v.z;
            As[(kc * 4 + 3) * APAD + m] = v.w;
        }
#pragma unroll
        for (int i = 0; i < 2; ++i) {
            int f  = tid * 2 + i;
            int kk = f >> 4;
            int nc = f & 15;
            float4 v = ld4(B + (size_t)(k0 + kk) * Nc + n0 + nc * 4);
            *reinterpret_cast<float4*>(&Bs[kk * TILE_N + nc * 4]) = v;
        }
        __syncthreads();

#pragma unroll
        for (int k = 0; k < TILE_K; ++k) {
            float4 a = *reinterpret_cast<const float4*>(&As[k * APAD + ty * 4]);
            float4 b = *reinterpret_cast<const float4*>(&Bs[k * TILE_N + tx * 4]);
            acc[0][0] += a.x * b.x; acc[0][1] += a.x * b.y; acc[0][2] += a.x * b.z; acc[0][3] += a.x * b.w;
            acc[1][0] += a.y * b.x; acc[1][1] += a.y * b.y; acc[1][2] += a.y * b.z; acc[1][3] += a.y * b.w;
            acc[2][0] += a.z * b.x; acc[2][1] += a.z * b.y; acc[2][2] += a.z * b.z; acc[2][3] += a.z * b.w;
            acc[3][0] += a.w * b.x; acc[3][1] += a.w * b.y; acc[3][2] += a.w * b.z; acc[3][3] += a.w * b.w;
        }
        __syncthreads();
    }

    float4 bv = make_float4(0.f, 0.f, 0.f, 0.f);
    if (bias) bv = ld4(bias + n0 + tx * 4);

#pragma unroll
    for (int i = 0; i < 4; ++i) {
        int gm = m0 + ty * 4 + i;
        if (gm < M) {
            float4 o;
            o.x = acc[i][0] + bv.x;
            o.y = acc[i][1] + bv.y;
            o.z = acc[i][2] + bv.z;
            o.w = acc[i][3] + bv.w;
            *reinterpret_cast<float4*>(C + (size_t)gm * Nc + n0 + tx * 4) = o;
        }
    }
}

// ---------------------------------------------------------------------------
// MFMA attention kernel. Block = 512 threads (8 waves), handles (b,h,64 rows).
// LDS (dynamic, ~91KB): khi/klo[128][72], qhi/qlo[64][72], vt[64][136],
//                       ps[64][136], selfE[64][10], rowfix[64], rinvS[64]
// XOR swizzle on the contiguous (k/d or j) dim by ((row&3)<<3) keeps MFMA
// fragment ds_read_b128 at <=2-way bank aliasing (free per m136).
// ---------------------------------------------------------------------------
#define KP 72     // pitch (ushorts) for khi/klo/qhi/qlo (64 + 8)
#define PP 136    // pitch (ushorts) for vt/ps (128 + 8)

__global__ __launch_bounds__(512)
void attn_ek(const float* __restrict__ proj1, const float* __restrict__ proj2,
             float* __restrict__ attn, float* __restrict__ Obuf,
             float* __restrict__ rowinv)
{
    extern __shared__ __align__(16) char smem_raw[];
    unsigned short* khi = (unsigned short*)smem_raw;          // 128*72
    unsigned short* klo = khi + 128 * KP;                     // 128*72
    unsigned short* qhi = klo + 128 * KP;                     // 64*72
    unsigned short* qlo = qhi + 64 * KP;                      // 64*72
    unsigned short* vt  = qlo + 64 * KP;                      // 64*136
    unsigned short* ps  = vt  + 64 * PP;                      // 64*136
    float* selfE  = (float*)(ps + 64 * PP);                   // 64*10
    float* rowfix = selfE + 640;                              // 64
    float* rinvS  = rowfix + 64;                              // 64
    float* Opart  = (float*)ps;                               // reuse after loop: [64][68]

    const int tid  = threadIdx.x;
    const int lane = tid & 63;
    const int wid  = tid >> 6;
    const int row0 = blockIdx.x * 64;
    const int h    = blockIdx.y;
    const int b    = blockIdx.z;
    const int bh   = b * HEADS_ + h;
    const size_t bN = (size_t)b * N_TOK;
    const size_t abase = ((size_t)bh * N_TOK + row0) * N_TOK;

    // ---------------- preamble ----------------
    if (tid < 64) rowfix[tid] = 0.f;

    // Q tile: 64 rows x 64 d, split hi/lo
    {
        int r = tid >> 3, q = tid & 7;
        int gr = row0 + r;
        float4 a = make_float4(0.f,0.f,0.f,0.f), c = a;
        if (gr < N_TOK) {
            const float* qp = proj1 + (bN + gr) * 1536 + h * 64 + q * 8;
            a = ld4(qp); c = ld4(qp + 4);
        }
        sh8 hi, lo; cvt8(a, c, hi, lo);
        int off = r * KP + ((q * 8) ^ ((r & 3) << 3));
        *(sh8*)(qhi + off) = hi;
        *(sh8*)(qlo + off) = lo;
    }

    // self-attn exp values (f32 dots from global; tiny)
    for (int idx = tid; idx < 640; idx += 512) {
        int r = idx / 10, c = idx - r * 10;
        int gr = row0 + r;
        if (gr < 2000) {
            int gj = (gr / 10) * 10 + c;
            const float* qp = proj2 + (bN + gr) * 1024 + h * 64;
            const float* kp = proj2 + (bN + gj) * 1024 + 512 + h * 64;
            float acc = 0.f;
#pragma unroll
            for (int d = 0; d < 16; ++d) {
                float4 qa = ld4(qp + 4 * d), ka = ld4(kp + 4 * d);
                acc += qa.x * ka.x + qa.y * ka.y + qa.z * ka.z + qa.w * ka.w;
            }
            selfE[r * 10 + c] = __expf(acc * SCALE_);
        }
    }
    __syncthreads();

    // hoist Q fragments (constant over the K loop)
    const int rt = wid & 1;           // S/PV row tile (32 rows)
    const int ct = wid >> 1;          // S col tile (0..3)
    const int dt = (wid >> 1) & 1;    // PV d tile
    const int kh = wid >> 2;          // PV k half
    const int lj = lane & 31, g = lane >> 5;
    const int swl = (lane & 3) << 3;

    sh8 qh[4], ql[4];
    {
        const unsigned short* qb  = qhi + (32 * rt + lj) * KP;
        const unsigned short* qlb = qlo + (32 * rt + lj) * KP;
#pragma unroll
        for (int ks = 0; ks < 4; ++ks) {
            int off = (16 * ks + 8 * g) ^ swl;
            qh[ks] = *(const sh8*)(qb + off);
            ql[ks] = *(const sh8*)(qlb + off);
        }
    }

    const int alo = (row0 / 10) * 10;
    const int rmaxa = min(row0 + 63, 1999);
    const int ahi = (rmaxa / 10) * 10 + 10;

    float rs = 0.f;
    f32x16 oacc;
#pragma unroll
    for (int i = 0; i < 16; ++i) oacc[i] = 0.f;

    // ---------------- main loop over key/value col tiles ----------------
#pragma unroll 1
    for (int j0 = 0; j0 < 2048; j0 += 128) {
        // ---- stage K tile (128 x 64, split hi/lo) ----
        {
            int r = tid >> 2, q = tid & 3;
            bool v = (j0 + r) < N_TOK;
            float4 a = make_float4(0.f,0.f,0.f,0.f), b4 = a, c = a, d4 = a;
            if (v) {
                const float* kp = proj1 + (bN + j0 + r) * 1536 + 512 + h * 64 + q * 16;
                a = ld4(kp); b4 = ld4(kp + 4); c = ld4(kp + 8); d4 = ld4(kp + 12);
            }
            sh8 h0, l0, h1, l1;
            cvt8(a, b4, h0, l0); cvt8(c, d4, h1, l1);
            int sw = (r & 3) << 3;
            unsigned short* k0 = khi + r * KP;
            unsigned short* k1 = klo + r * KP;
            *(sh8*)(k0 + ((q * 16) ^ sw))     = h0;
            *(sh8*)(k1 + ((q * 16) ^ sw))     = l0;
            *(sh8*)(k0 + ((q * 16 + 8) ^ sw)) = h1;
            *(sh8*)(k1 + ((q * 16 + 8) ^ sw)) = l1;
        }
        // ---- stage V^T tile (64 d x 128 j, bf16) ----
        {
            int c = tid & 63, p = tid >> 6;
            int swd = (c & 3) << 3;
            const float* vbase = proj1 + bN * 1536 + 1024 + h * 64 + c;
            unsigned short* vrow = vt + c * PP;
#pragma unroll
            for (int m = 0; m < 8; ++m) {
                int jp = p * 8 + m;
                int j  = j0 + 2 * jp;
                float v0 = (j     < N_TOK) ? vbase[(size_t)j * 1536]       : 0.f;
                float v1 = (j + 1 < N_TOK) ? vbase[(size_t)(j + 1) * 1536] : 0.f;
                unsigned pk = (unsigned)f2bf(v0) | ((unsigned)f2bf(v1) << 16);
                *(unsigned*)(vrow + ((2 * jp) ^ swd)) = pk;
            }
        }
        __syncthreads();   // B0

        // ---- S = Q K^T (split bf16, 3 mfma per k-step), exp, stores ----
        {
            sh8 kfh[4], kfl[4];
            const unsigned short* kb  = khi + (32 * ct + lj) * KP;
            const unsigned short* klb = klo + (32 * ct + lj) * KP;
#pragma unroll
            for (int ks = 0; ks < 4; ++ks) {
                int off = (16 * ks + 8 * g) ^ swl;
                kfh[ks] = *(const sh8*)(kb + off);
                kfl[ks] = *(const sh8*)(klb + off);
            }
            f32x16 s;
#pragma unroll
            for (int i = 0; i < 16; ++i) s[i] = 0.f;
#pragma unroll
            for (int ks = 0; ks < 4; ++ks) {
                s = __builtin_amdgcn_mfma_f32_32x32x16_bf16(qh[ks], kfh[ks], s, 0, 0, 0);
                s = __builtin_amdgcn_mfma_f32_32x32x16_bf16(qh[ks], kfl[ks], s, 0, 0, 0);
                s = __builtin_amdgcn_mfma_f32_32x32x16_bf16(ql[ks], kfh[ks], s, 0, 0, 0);
            }
            const int cin = 32 * ct + lj;          // col within 128 tile
            const int gj  = j0 + cin;
            const bool jv = gj < N_TOK;
            float* ap = attn + abase + gj;
#pragma unroll
            for (int reg = 0; reg < 16; ++reg) {
                int rowr = 32 * rt + (reg & 3) + 8 * (reg >> 2) + 4 * g;
                float e = 0.f;
                if (jv) e = __expf(s[reg] * SCALE_);
                if (jv && (row0 + rowr) < N_TOK) ap[(size_t)rowr * N_TOK] = e;
                ps[rowr * PP + (cin ^ ((reg & 3) << 3))] = f2bf(e);
            }
        }
        __syncthreads();   // B1

        // ---- diag-block self override (rare tiles) ----
        if (alo < j0 + 128 && ahi > j0) {
            if (tid < 64) {
                int r = tid, gr = row0 + r;
                if (gr < 2000) {
                    int a0 = (gr / 10) * 10;
                    int sw = (r & 3) << 3;
                    float dfix = 0.f;
#pragma unroll
                    for (int c = 0; c < 10; ++c) {
                        int gj = a0 + c;
                        int cin = gj - j0;
                        if (cin >= 0 && cin < 128) {
                            int pi = r * PP + (cin ^ sw);
                            float oldv = bf2f(ps[pi]);
                            float ev = selfE[r * 10 + c];
                            dfix += ev - oldv;
                            ps[pi] = f2bf(ev);
                            attn[abase + (size_t)r * N_TOK + gj] = ev;
                        }
                    }
                    rowfix[r] += dfix;
                }
            }
        }
        __syncthreads();   // B2

        // ---- rowsum partials from ps ----
        {
            int r = tid >> 3, q = tid & 7;
            int sw = (r & 3) << 3;
            const unsigned short* pr = ps + r * PP;
            sh8 e0 = *(const sh8*)(pr + ((16 * q) ^ sw));
            sh8 e1 = *(const sh8*)(pr + ((16 * q + 8) ^ sw));
            float ssum = 0.f;
#pragma unroll
            for (int i = 0; i < 8; ++i)
                ssum += bf2f((unsigned short)e0[i]) + bf2f((unsigned short)e1[i]);
            rs += ssum;
        }
        // ---- PV: O += P V (bf16 mfma), k-split across wave halves ----
        {
            const unsigned short* pa = ps + (32 * rt + lj) * PP;
            const unsigned short* vb = vt + (32 * dt + lj) * PP;
#pragma unroll
            for (int ks = 0; ks < 4; ++ks) {
                int off = (64 * kh + 16 * ks + 8 * g) ^ swl;
                sh8 a = *(const sh8*)(pa + off);
                sh8 v = *(const sh8*)(vb + off);
                oacc = __builtin_amdgcn_mfma_f32_32x32x16_bf16(a, v, oacc, 0, 0, 0);
            }
        }
        __syncthreads();   // B3
    }

    // ---------------- epilogue ----------------
    // rowsums -> rinv
    {
        int r = tid >> 3, q = tid & 7;
        float v = rs;
        v += __shfl_xor(v, 1);
        v += __shfl_xor(v, 2);
        v += __shfl_xor(v, 4);
        if (q == 0) {
            float tot = v + rowfix[r];
            float ri = 1.0f / tot;
            rinvS[r] = ri;
            if (row0 + r < N_TOK) rowinv[(size_t)bh * N_TOK + row0 + r] = ri;
        }
    }
    // merge PV k-halves via LDS (Opart overlays ps; all ps reads are done)
    if (kh == 1) {
#pragma unroll
        for (int reg = 0; reg < 16; ++reg) {
            int rowl = (reg & 3) + 8 * (reg >> 2) + 4 * g;
            Opart[(32 * rt + rowl) * 68 + 32 * dt + lj] = oacc[reg];
        }
    }
    __syncthreads();
    if (kh == 0) {
#pragma unroll
        for (int reg = 0; reg < 16; ++reg) {
            int rowl = (reg & 3) + 8 * (reg >> 2) + 4 * g;
            int rloc = 32 * rt + rowl;
            float val = oacc[reg] + Opart[rloc * 68 + 32 * dt + lj];
            val *= rinvS[rloc];
            int gr = row0 + rloc;
            if (gr < N_TOK)
                Obuf[(bN + gr) * 512 + h * 64 + 32 * dt + lj] = val;
        }
    }
}

// ---------------------------------------------------------------------------
// attn[row] *= rinv[row]  (in place, streaming)
// ---------------------------------------------------------------------------
__global__ __launch_bounds__(256)
void attn_scale(float* __restrict__ attn, const float* __restrict__ rowinv)
{
    const int row = blockIdx.x;
    const int bh  = blockIdx.y;
    const size_t base = ((size_t)bh * N_TOK + row) * (size_t)N_TOK;
    const float riv = rowinv[(size_t)bh * N_TOK + row];
    float* p = attn + base;
    int head = (int)((4 - (base & 3)) & 3);
    for (int i = threadIdx.x; i < head; i += 256) p[i] *= riv;
    int nmid = (N_TOK - head) >> 2;
    float4* p4 = reinterpret_cast<float4*>(p + head);
    for (int i = threadIdx.x; i < nmid; i += 256) {
        float4 v = p4[i];
        v.x *= riv; v.y *= riv; v.z *= riv; v.w *= riv;
        p4[i] = v;
    }
    for (int i = head + nmid * 4 + threadIdx.x; i < N_TOK; i += 256) p[i] *= riv;
}

// ---------------------------------------------------------------------------
extern "C" void kernel_launch(void* const* d_in, const int* in_sizes, int n_in,
                              void* d_out, int out_size, void* d_ws, size_t ws_size,
                              hipStream_t stream)
{
    const float* x         = (const float*)d_in[0];
    const float* w_qkv     = (const float*)d_in[1];
    const float* w_qk_self = (const float*)d_in[2];
    const float* w_out     = (const float*)d_in[3];
    const float* b_out     = (const float*)d_in[4];

    float* out  = (float*)d_out;                       // [8036,512]
    float* attn = out + (size_t)MROWS * 512;           // [4,8,2009,2009]

    float* proj1  = (float*)d_ws;                      // [8036,1536]
    float* proj2  = proj1 + (size_t)MROWS * 1536;      // [8036,1024]
    float* Obuf   = proj2 + (size_t)MROWS * 1024;      // [8036,512]
    float* rowinv = Obuf + (size_t)MROWS * 512;        // [32,2009]
    // ws usage: 99,003,520 bytes

    const int smem_attn = (2 * 128 * KP + 2 * 64 * KP + 2 * 64 * PP) * 2
                        + (640 + 64 + 64) * 4;         // 93,184 B
    hipFuncSetAttribute((const void*)attn_ek,
                        hipFuncAttributeMaxDynamicSharedMemorySize, smem_attn);

    const int mt = cdiv(MROWS, TILE_M);   // 126

    dim3 g1(mt, 1536 / TILE_N);
    gemm_f32<<<g1, 256, 0, stream>>>(x, w_qkv, proj1, nullptr, MROWS, 1536, 512);

    dim3 g2(mt, 1024 / TILE_N);
    gemm_f32<<<g2, 256, 0, stream>>>(x, w_qk_self, proj2, nullptr, MROWS, 1024, 512);

    dim3 ga(32, HEADS_, BATCH_);
    attn_ek<<<ga, 512, smem_attn, stream>>>(proj1, proj2, attn, Obuf, rowinv);

    dim3 gs(N_TOK, BATCH_ * HEADS_);
    attn_scale<<<gs, 256, 0, stream>>>(attn, rowinv);

    dim3 g3(mt, 512 / TILE_N);
    gemm_f32<<<g3, 256, 0, stream>>>(Obuf, w_out, out, b_out, MROWS, 512, 512);
}

// Round 3
// 1085.187 us; speedup vs baseline: 2.7652x; 1.1628x over previous
//
#include <hip/hip_runtime.h>
#include <hip/hip_bf16.h>

// ---------------------------------------------------------------------------
// AgentAwareAttention (MI355X / gfx950) — Round 3: fragment-major preconvert,
// two-pass normalized attention (no scale pass), global_load_lds staging.
// Pipeline:
//   1) gemm_f32: proj1 = x @ w_qkv       [8036 x 1536] (q|k|v)
//   2) gemm_f32: proj2 = x @ w_qk_self   [8036 x 1024] (qs|ks)
//   3) selfE_k:  selfE[bh][r][0..10) = exp(scale * qs_r . ks_j) (diag blocks)
//   4) convert_kv: proj1 K,V -> Khg/Klg (bf16 hi/lo, fragment-major) + Vtg
//      (V^T bf16 fragment-major), overwriting proj2's region (dead after 3)
//   5) attn_rowsum (pass A): hi-only QK MFMA -> rowinv
//   6) attn_pv (pass B): split-bf16 QK -> p = e*rinv -> attn (normalized),
//      PV MFMA -> Obuf (normalized)
//   7) gemm_f32: out = Obuf @ w_out + b_out
// ---------------------------------------------------------------------------

#define N_TOK   2009
#define NPAD    2048
#define NTILES  16
#define BATCH_  4
#define HEADS_  8
#define MROWS   8036
#define SCALE_  0.125f

typedef __attribute__((ext_vector_type(8)))  short sh8;     // 8 bf16
typedef __attribute__((ext_vector_type(16))) float f32x16;  // mfma 32x32 acc

static inline int cdiv(int a, int b) { return (a + b - 1) / b; }

__device__ __forceinline__ float4 ld4(const float* p) {
    return *reinterpret_cast<const float4*>(p);
}
__device__ __forceinline__ unsigned short f2bf(float f) {
    __hip_bfloat16 h = __float2bfloat16(f);
    return *reinterpret_cast<unsigned short*>(&h);
}
__device__ __forceinline__ float bf2f(unsigned short u) {
    return __uint_as_float(((unsigned)u) << 16);
}
__device__ __forceinline__ void cvt8(const float4& a, const float4& b, sh8& hi, sh8& lo) {
    float f[8] = {a.x, a.y, a.z, a.w, b.x, b.y, b.z, b.w};
#pragma unroll
    for (int i = 0; i < 8; ++i) {
        unsigned short h = f2bf(f[i]);
        hi[i] = (short)h;
        lo[i] = (short)f2bf(f[i] - bf2f(h));
    }
}
__device__ __forceinline__ void cvt8p(const float4& a, const float4& b, sh8& hi) {
#pragma unroll
    for (int i = 0; i < 4; ++i) {
        hi[i]     = (short)f2bf((&a.x)[i]);
        hi[4 + i] = (short)f2bf((&b.x)[i]);
    }
}
// async global -> LDS, 16B per lane (dest = wave-uniform base + lane*16)
typedef const __attribute__((address_space(1))) void gas_void;
typedef __attribute__((address_space(3))) void las_void;
__device__ __forceinline__ void gll16(const void* g, void* l) {
    __builtin_amdgcn_global_load_lds((gas_void*)g, (las_void*)l, 16, 0, 0);
}

// ---------------------------------------------------------------------------
// Tiled f32 GEMM (unchanged): C[M,Nc] = A[M,K]*B[K,Nc] (+bias)
// ---------------------------------------------------------------------------
#define TILE_M 64
#define TILE_N 64
#define TILE_K 32
#define APAD   68

__global__ __launch_bounds__(256)
void gemm_f32(const float* __restrict__ A, const float* __restrict__ B,
              float* __restrict__ C, const float* __restrict__ bias,
              int M, int Nc, int K)
{
    __shared__ float As[TILE_K * APAD];
    __shared__ float Bs[TILE_K * TILE_N];

    const int tid = threadIdx.x;
    const int m0  = blockIdx.x * TILE_M;
    const int n0  = blockIdx.y * TILE_N;
    const int tx  = tid & 15;
    const int ty  = tid >> 4;

    float acc[4][4] = {};

    for (int k0 = 0; k0 < K; k0 += TILE_K) {
#pragma unroll
        for (int i = 0; i < 2; ++i) {
            int f  = tid * 2 + i;
            int m  = f >> 3;
            int kc = f & 7;
            float4 v = make_float4(0.f, 0.f, 0.f, 0.f);
            int gm = m0 + m;
            if (gm < M) v = ld4(A + (size_t)gm * K + k0 + kc * 4);
            As[(kc * 4 + 0) * APAD + m] = v.x;
            As[(kc * 4 + 1) * APAD + m] = v.y;
            As[(kc * 4 + 2) * APAD + m] = v.z;
            As[(kc * 4 + 3) * APAD + m] = v.w;
        }
#pragma unroll
        for (int i = 0; i < 2; ++i) {
            int f  = tid * 2 + i;
            int kk = f >> 4;
            int nc = f & 15;
            float4 v = ld4(B + (size_t)(k0 + kk) * Nc + n0 + nc * 4);
            *reinterpret_cast<float4*>(&Bs[kk * TILE_N + nc * 4]) = v;
        }
        __syncthreads();

#pragma unroll
        for (int k = 0; k < TILE_K; ++k) {
            float4 a = *reinterpret_cast<const float4*>(&As[k * APAD + ty * 4]);
            float4 b = *reinterpret_cast<const float4*>(&Bs[k * TILE_N + tx * 4]);
            acc[0][0] += a.x * b.x; acc[0][1] += a.x * b.y; acc[0][2] += a.x * b.z; acc[0][3] += a.x * b.w;
            acc[1][0] += a.y * b.x; acc[1][1] += a.y * b.y; acc[1][2] += a.y * b.z; acc[1][3] += a.y * b.w;
            acc[2][0] += a.z * b.x; acc[2][1] += a.z * b.y; acc[2][2] += a.z * b.z; acc[2][3] += a.z * b.w;
            acc[3][0] += a.w * b.x; acc[3][1] += a.w * b.y; acc[3][2] += a.w * b.z; acc[3][3] += a.w * b.w;
        }
        __syncthreads();
    }

    float4 bv = make_float4(0.f, 0.f, 0.f, 0.f);
    if (bias) bv = ld4(bias + n0 + tx * 4);

#pragma unroll
    for (int i = 0; i < 4; ++i) {
        int gm = m0 + ty * 4 + i;
        if (gm < M) {
            float4 o;
            o.x = acc[i][0] + bv.x;
            o.y = acc[i][1] + bv.y;
            o.z = acc[i][2] + bv.z;
            o.w = acc[i][3] + bv.w;
            *reinterpret_cast<float4*>(C + (size_t)gm * Nc + n0 + tx * 4) = o;
        }
    }
}

// ---------------------------------------------------------------------------
// selfE: per (bh, agent a): 10x10 exp(scale * qs_r . ks_j)
// ---------------------------------------------------------------------------
__global__ __launch_bounds__(256)
void selfE_k(const float* __restrict__ proj2, float* __restrict__ selfE)
{
    __shared__ float qs[10][64];
    __shared__ float ks[10][68];
    const int a = blockIdx.x;          // 0..199
    const int h = blockIdx.y & 7;
    const int b = blockIdx.y >> 3;
    const size_t rowbase = (size_t)b * N_TOK + a * 10;

    for (int i = threadIdx.x; i < 320; i += 256) {
        int r = i >> 4;                 // 0..19
        int c = (i & 15) * 4;
        const float* src = proj2 + (rowbase + (r % 10)) * 1024
                         + (r < 10 ? 0 : 512) + h * 64 + c;
        float4 v = ld4(src);
        if (r < 10) *reinterpret_cast<float4*>(&qs[r][c]) = v;
        else        *reinterpret_cast<float4*>(&ks[r - 10][c]) = v;
    }
    __syncthreads();
    if (threadIdx.x < 100) {
        int r = threadIdx.x / 10, c = threadIdx.x % 10;
        float acc = 0.f;
#pragma unroll 8
        for (int d = 0; d < 64; ++d) acc += qs[r][d] * ks[c][d];
        int bh = b * HEADS_ + h;
        selfE[((size_t)bh * 2000 + a * 10 + r) * 10 + c] = __expf(acc * SCALE_);
    }
}

// ---------------------------------------------------------------------------
// convert K -> Khg/Klg (hi/lo bf16, fragment-major [bh][t][kc][row]x16B)
//         V -> Vtg (V^T bf16, fragment-major [bh][t][jc][d]x16B)
// ---------------------------------------------------------------------------
__global__ __launch_bounds__(256)
void convert_kv(const float* __restrict__ proj1,
                unsigned short* __restrict__ Khg, unsigned short* __restrict__ Klg,
                unsigned short* __restrict__ Vtg)
{
    __shared__ float vtile[128][66];
    const int t  = blockIdx.x;          // 0..15
    const int h  = blockIdx.y & 7;
    const int b  = blockIdx.y >> 3;
    const int bh = blockIdx.y;
    const size_t bN = (size_t)b * N_TOK;
    const size_t tbase = ((size_t)bh * NTILES + t) * 8192;   // halfs
    const int tid = threadIdx.x;

    // ---- K rows ----
    {
        int r = tid >> 1, q = tid & 1;
        int gj = t * 128 + r;
        float4 f[8];
        if (gj < N_TOK) {
            const float* kp = proj1 + (bN + gj) * 1536 + 512 + h * 64 + q * 32;
#pragma unroll
            for (int i = 0; i < 8; ++i) f[i] = ld4(kp + 4 * i);
        } else {
#pragma unroll
            for (int i = 0; i < 8; ++i) f[i] = make_float4(0.f, 0.f, 0.f, 0.f);
        }
#pragma unroll
        for (int cp = 0; cp < 4; ++cp) {
            sh8 hi, lo;
            cvt8(f[2 * cp], f[2 * cp + 1], hi, lo);
            int kc = q * 4 + cp;
            size_t off = tbase + ((size_t)kc * 128 + r) * 8;
            *reinterpret_cast<sh8*>(Khg + off) = hi;
            *reinterpret_cast<sh8*>(Klg + off) = lo;
        }
    }
    // ---- V tile stage (f32) ----
    {
        int r = tid >> 1, q = tid & 1;
        int gj = t * 128 + r;
        const float* vp = proj1 + (bN + gj) * 1536 + 1024 + h * 64 + q * 32;
#pragma unroll
        for (int i = 0; i < 8; ++i) {
            float4 v = (gj < N_TOK) ? ld4(vp + 4 * i) : make_float4(0.f, 0.f, 0.f, 0.f);
            *reinterpret_cast<float4*>(&vtile[r][q * 32 + 4 * i]) = v;
        }
    }
    __syncthreads();
    // ---- transpose-write V^T fragments ----
    {
        int d = tid & 63, jg = tid >> 6;   // jg 0..3
#pragma unroll
        for (int jj = 0; jj < 4; ++jj) {
            int jc = jg * 4 + jj;
            sh8 pk;
#pragma unroll
            for (int i = 0; i < 8; ++i) pk[i] = (short)f2bf(vtile[jc * 8 + i][d]);
            *reinterpret_cast<sh8*>(Vtg + tbase + ((size_t)jc * 64 + d) * 8) = pk;
        }
    }
}

// ---------------------------------------------------------------------------
// pass A: rowsums (hi-only QK, 4 MFMA per tile) -> rowinv
// grid: 1024 blocks (XCD-swizzled), 512 threads
// ---------------------------------------------------------------------------
__global__ __launch_bounds__(512, 4)
void attn_rowsum(const float* __restrict__ proj1,
                 const unsigned short* __restrict__ Khg,
                 const float* __restrict__ selfE,
                 float* __restrict__ rowinv)
{
    __shared__ __align__(16) unsigned short KhS[8192];   // [kc][row]x8 halfs (16KB)
    __shared__ float selfS[640];
    __shared__ float partial[256];

    const int w  = ((blockIdx.x & 7) << 7) | (blockIdx.x >> 3);  // XCD swizzle
    const int bx = w & 31;
    const int bh = w >> 5;
    const int h  = bh & 7, b = bh >> 3;
    const int tid = threadIdx.x, lane = tid & 63, wid = tid >> 6;
    const int row0 = bx * 64;
    const size_t bN = (size_t)b * N_TOK;

    for (int i = tid; i < 640; i += 512) {
        int r = i / 10, c = i - r * 10;
        int gr = row0 + r;
        selfS[i] = (gr < 2000) ? selfE[((size_t)bh * 2000 + gr) * 10 + c] : 0.f;
    }
    // Q stage (hi only) into KhS as [kc=q][row=r]
    {
        int r = lane, q = wid;
        int gr = row0 + r;
        float4 a = make_float4(0.f, 0.f, 0.f, 0.f), b4 = a;
        if (gr < N_TOK) {
            const float* qp = proj1 + (bN + gr) * 1536 + h * 64 + q * 8;
            a = ld4(qp); b4 = ld4(qp + 4);
        }
        sh8 hi; cvt8p(a, b4, hi);
        *reinterpret_cast<sh8*>(KhS + ((size_t)q * 64 + r) * 8) = hi;
    }
    __syncthreads();

    const int rt = wid & 1, ct = wid >> 1;
    const int lj = lane & 31, g = lane >> 5;
    sh8 qh[4];
#pragma unroll
    for (int ks = 0; ks < 4; ++ks)
        qh[ks] = *reinterpret_cast<const sh8*>(KhS + ((2 * ks + g) * 64 + 32 * rt + lj) * 8);
    __syncthreads();

    const unsigned short* ktiles = Khg + (size_t)bh * NTILES * 8192;
#pragma unroll
    for (int i = 0; i < 2; ++i)
        gll16(ktiles + i * 4096 + wid * 512 + lane * 8,
              (char*)KhS + i * 8192 + wid * 1024 + lane * 16);

    float rsacc[16];
#pragma unroll
    for (int i = 0; i < 16; ++i) rsacc[i] = 0.f;

    const int alo = (row0 / 10) * 10;
    const int rmax = row0 + 63 < 1999 ? row0 + 63 : 1999;
    const int ahi = (rmax / 10) * 10 + 10;

    for (int t = 0; t < NTILES; ++t) {
        __syncthreads();                       // staging complete
        sh8 kf[4];
#pragma unroll
        for (int ks = 0; ks < 4; ++ks)
            kf[ks] = *reinterpret_cast<const sh8*>(KhS + ((2 * ks + g) * 128 + 32 * ct + lj) * 8);
        f32x16 s;
#pragma unroll
        for (int i = 0; i < 16; ++i) s[i] = 0.f;
#pragma unroll
        for (int ks = 0; ks < 4; ++ks)
            s = __builtin_amdgcn_mfma_f32_32x32x16_bf16(qh[ks], kf[ks], s, 0, 0, 0);
        __syncthreads();                       // K reads done
        if (t + 1 < NTILES) {
            const unsigned short* kt = ktiles + (size_t)(t + 1) * 8192;
#pragma unroll
            for (int i = 0; i < 2; ++i)
                gll16(kt + i * 4096 + wid * 512 + lane * 8,
                      (char*)KhS + i * 8192 + wid * 1024 + lane * 16);
        }
        const int cin = 32 * ct + lj;
        const int gj  = t * 128 + cin;
        if (gj < N_TOK) {
            const bool dtile = (alo < t * 128 + 128) && (ahi > t * 128);
#pragma unroll
            for (int reg = 0; reg < 16; ++reg) {
                int rowr = 32 * rt + (reg & 3) + 8 * (reg >> 2) + 4 * g;
                int gr = row0 + rowr;
                float e = __expf(s[reg] * SCALE_);
                if (dtile && gr < 2000) {
                    int a0 = (gr / 10) * 10;
                    unsigned cc = (unsigned)(gj - a0);
                    if (cc < 10u) e = selfS[rowr * 10 + (int)cc];
                }
                rsacc[reg] += e;
            }
        }
    }

#pragma unroll
    for (int reg = 0; reg < 16; ++reg) {
        float v = rsacc[reg];
        v += __shfl_xor(v, 1);  v += __shfl_xor(v, 2);
        v += __shfl_xor(v, 4);  v += __shfl_xor(v, 8);
        v += __shfl_xor(v, 16);
        rsacc[reg] = v;
    }
    if (lj == 0) {
#pragma unroll
        for (int reg = 0; reg < 16; ++reg) {
            int rowr = 32 * rt + (reg & 3) + 8 * (reg >> 2) + 4 * g;
            partial[ct * 64 + rowr] = rsacc[reg];
        }
    }
    __syncthreads();
    if (tid < 64) {
        float ssum = partial[tid] + partial[64 + tid] + partial[128 + tid] + partial[192 + tid];
        int gr = row0 + tid;
        rowinv[(size_t)bh * NPAD + row0 + tid] = (gr < N_TOK) ? 1.0f / ssum : 0.f;
    }
}

// ---------------------------------------------------------------------------
// pass B: split-bf16 QK -> p = e*rinv -> attn (normalized) ; PV -> Obuf
// grid: 1024 blocks (XCD-swizzled), 512 threads, 68,352 B dynamic LDS
// ---------------------------------------------------------------------------
__global__ __launch_bounds__(512, 4)
void attn_pv(const float* __restrict__ proj1,
             const unsigned short* __restrict__ Khg,
             const unsigned short* __restrict__ Klg,
             const unsigned short* __restrict__ Vtg,
             const float* __restrict__ selfE,
             const float* __restrict__ rowinv,
             float* __restrict__ attn, float* __restrict__ Obuf)
{
    extern __shared__ __align__(16) char smem[];
    unsigned short* KhS = (unsigned short*)smem;    // 8192 halfs
    unsigned short* KlS = KhS + 8192;
    unsigned short* VtS = KlS + 8192;               // [jc][d]x8
    unsigned short* psS = VtS + 8192;               // [jc][row]x8
    float* selfS = (float*)(psS + 8192);            // 640
    float* rinvS = selfS + 640;                     // 64
    float* Opart = (float*)psS;                     // epilogue alias [64][64]

    const int w  = ((blockIdx.x & 7) << 7) | (blockIdx.x >> 3);
    const int bx = w & 31;
    const int bh = w >> 5;
    const int h  = bh & 7, b = bh >> 3;
    const int tid = threadIdx.x, lane = tid & 63, wid = tid >> 6;
    const int row0 = bx * 64;
    const size_t bN = (size_t)b * N_TOK;
    const size_t abase = ((size_t)bh * N_TOK + row0) * N_TOK;

    for (int i = tid; i < 640; i += 512) {
        int r = i / 10, c = i - r * 10;
        int gr = row0 + r;
        selfS[i] = (gr < 2000) ? selfE[((size_t)bh * 2000 + gr) * 10 + c] : 0.f;
    }
    if (tid < 64) rinvS[tid] = rowinv[(size_t)bh * NPAD + row0 + tid];

    // Q stage hi+lo (aliased into KhS/KlS)
    {
        int r = lane, q = wid;
        int gr = row0 + r;
        float4 a = make_float4(0.f, 0.f, 0.f, 0.f), b4 = a;
        if (gr < N_TOK) {
            const float* qp = proj1 + (bN + gr) * 1536 + h * 64 + q * 8;
            a = ld4(qp); b4 = ld4(qp + 4);
        }
        sh8 hi, lo; cvt8(a, b4, hi, lo);
        *reinterpret_cast<sh8*>(KhS + ((size_t)q * 64 + r) * 8) = hi;
        *reinterpret_cast<sh8*>(KlS + ((size_t)q * 64 + r) * 8) = lo;
    }
    __syncthreads();

    const int rt = wid & 1, ct = wid >> 1;
    const int dt = (wid >> 1) & 1, kh = wid >> 2;
    const int lj = lane & 31, g = lane >> 5;
    sh8 qh[4], ql[4];
#pragma unroll
    for (int ks = 0; ks < 4; ++ks) {
        qh[ks] = *reinterpret_cast<const sh8*>(KhS + ((2 * ks + g) * 64 + 32 * rt + lj) * 8);
        ql[ks] = *reinterpret_cast<const sh8*>(KlS + ((2 * ks + g) * 64 + 32 * rt + lj) * 8);
    }
    __syncthreads();

    const unsigned short* khT = Khg + (size_t)bh * NTILES * 8192;
    const unsigned short* klT = Klg + (size_t)bh * NTILES * 8192;
    const unsigned short* vtT = Vtg + (size_t)bh * NTILES * 8192;

#define STAGE_K(T) do { size_t tb = (size_t)(T) * 8192;                                  \
    _Pragma("unroll") for (int i = 0; i < 2; ++i) {                                      \
        gll16(khT + tb + i * 4096 + wid * 512 + lane * 8,                                \
              (char*)KhS + i * 8192 + wid * 1024 + lane * 16);                           \
        gll16(klT + tb + i * 4096 + wid * 512 + lane * 8,                                \
              (char*)KlS + i * 8192 + wid * 1024 + lane * 16); } } while (0)
#define STAGE_V(T) do { size_t tb = (size_t)(T) * 8192;                                  \
    _Pragma("unroll") for (int i = 0; i < 2; ++i)                                        \
        gll16(vtT + tb + i * 4096 + wid * 512 + lane * 8,                                \
              (char*)VtS + i * 8192 + wid * 1024 + lane * 16); } while (0)

    STAGE_K(0);
    STAGE_V(0);

    const int alo = (row0 / 10) * 10;
    const int rmax = row0 + 63 < 1999 ? row0 + 63 : 1999;
    const int ahi = (rmax / 10) * 10 + 10;

    f32x16 oacc;
#pragma unroll
    for (int i = 0; i < 16; ++i) oacc[i] = 0.f;

    for (int t = 0; t < NTILES; ++t) {
        __syncthreads();                       // B0: staging complete
        // ---- S = QK^T (split bf16, 3 mfma / k-step) ----
        sh8 kfh[4], kfl[4];
#pragma unroll
        for (int ks = 0; ks < 4; ++ks) {
            kfh[ks] = *reinterpret_cast<const sh8*>(KhS + ((2 * ks + g) * 128 + 32 * ct + lj) * 8);
            kfl[ks] = *reinterpret_cast<const sh8*>(KlS + ((2 * ks + g) * 128 + 32 * ct + lj) * 8);
        }
        f32x16 s;
#pragma unroll
        for (int i = 0; i < 16; ++i) s[i] = 0.f;
#pragma unroll
        for (int ks = 0; ks < 4; ++ks) {
            s = __builtin_amdgcn_mfma_f32_32x32x16_bf16(qh[ks], kfh[ks], s, 0, 0, 0);
            s = __builtin_amdgcn_mfma_f32_32x32x16_bf16(qh[ks], kfl[ks], s, 0, 0, 0);
            s = __builtin_amdgcn_mfma_f32_32x32x16_bf16(ql[ks], kfh[ks], s, 0, 0, 0);
        }
        // ---- exp, override, normalize, store attn + ps ----
        const int cin = 32 * ct + lj;
        const int gj  = t * 128 + cin;
        const bool jv = gj < N_TOK;
        const bool dtile = (alo < t * 128 + 128) && (ahi > t * 128);
        float* ap = attn + abase + gj;
#pragma unroll
        for (int reg = 0; reg < 16; ++reg) {
            int rowr = 32 * rt + (reg & 3) + 8 * (reg >> 2) + 4 * g;
            int gr = row0 + rowr;
            float e = 0.f;
            if (jv && gr < N_TOK) e = __expf(s[reg] * SCALE_);
            if (dtile && jv && gr < 2000) {
                int a0 = (gr / 10) * 10;
                unsigned cc = (unsigned)(gj - a0);
                if (cc < 10u) e = selfS[rowr * 10 + (int)cc];
            }
            float p = e * rinvS[rowr];
            if (jv && gr < N_TOK) ap[(size_t)rowr * N_TOK] = p;
            psS[((4 * ct + (lj >> 3)) * 64 + rowr) * 8 + (lj & 7)] = f2bf(p);
        }
        __syncthreads();                       // B2: K reads done + ps visible
        if (t + 1 < NTILES) STAGE_K(t + 1);    // overlaps PV
        // ---- PV: O += P V ----
#pragma unroll
        for (int ks = 0; ks < 4; ++ks) {
            int jc = 8 * kh + 2 * ks + g;
            sh8 pa = *reinterpret_cast<const sh8*>(psS + (jc * 64 + 32 * rt + lj) * 8);
            sh8 vf = *reinterpret_cast<const sh8*>(VtS + (jc * 64 + 32 * dt + lj) * 8);
            oacc = __builtin_amdgcn_mfma_f32_32x32x16_bf16(pa, vf, oacc, 0, 0, 0);
        }
        __syncthreads();                       // B3: V/ps reads done
        if (t + 1 < NTILES) STAGE_V(t + 1);
    }

    // ---- epilogue: merge kh halves, write Obuf (already normalized) ----
    if (kh == 1) {
#pragma unroll
        for (int reg = 0; reg < 16; ++reg) {
            int rowl = (reg & 3) + 8 * (reg >> 2) + 4 * g;
            Opart[(32 * rt + rowl) * 64 + 32 * dt + lj] = oacc[reg];
        }
    }
    __syncthreads();
    if (kh == 0) {
#pragma unroll
        for (int reg = 0; reg < 16; ++reg) {
            int rowl = (reg & 3) + 8 * (reg >> 2) + 4 * g;
            int rloc = 32 * rt + rowl;
            float val = oacc[reg] + Opart[rloc * 64 + 32 * dt + lj];
            int gr = row0 + rloc;
            if (gr < N_TOK)
                Obuf[(bN + gr) * 512 + h * 64 + 32 * dt + lj] = val;
        }
    }
#undef STAGE_K
#undef STAGE_V
}

// ---------------------------------------------------------------------------
extern "C" void kernel_launch(void* const* d_in, const int* in_sizes, int n_in,
                              void* d_out, int out_size, void* d_ws, size_t ws_size,
                              hipStream_t stream)
{
    const float* x         = (const float*)d_in[0];
    const float* w_qkv     = (const float*)d_in[1];
    const float* w_qk_self = (const float*)d_in[2];
    const float* w_out     = (const float*)d_in[3];
    const float* b_out     = (const float*)d_in[4];

    float* out  = (float*)d_out;                       // [8036,512]
    float* attn = out + (size_t)MROWS * 512;           // [4,8,2009,2009]

    // workspace layout (floats):
    float* proj1 = (float*)d_ws;                       // 12,343,296
    float* p2    = proj1 + (size_t)MROWS * 1536;       // proj2 region, 8,228,864
    unsigned short* Khg = (unsigned short*)p2;         // 4,194,304 halfs (8MB)
    unsigned short* Klg = Khg + 4194304;
    unsigned short* Vtg = Klg + 4194304;               // ends at p2 + 6,291,456 floats
    float* proj2  = p2;                                // f32 view (before convert)
    float* Obuf   = p2 + (size_t)MROWS * 1024;         // 4,114,432
    float* rowinv = Obuf + (size_t)MROWS * 512;        // 32*2048 = 65,536
    float* selfE  = rowinv + 65536;                    // 640,000
    // total: 101,568,512 bytes

    const int smem_pv = 4 * 8192 * 2 + 640 * 4 + 64 * 4;   // 68,352 B
    hipFuncSetAttribute((const void*)attn_pv,
                        hipFuncAttributeMaxDynamicSharedMemorySize, smem_pv);

    const int mt = cdiv(MROWS, TILE_M);   // 126

    dim3 g1(mt, 1536 / TILE_N);
    gemm_f32<<<g1, 256, 0, stream>>>(x, w_qkv, proj1, nullptr, MROWS, 1536, 512);

    dim3 g2(mt, 1024 / TILE_N);
    gemm_f32<<<g2, 256, 0, stream>>>(x, w_qk_self, proj2, nullptr, MROWS, 1024, 512);

    dim3 gs(200, 32);
    selfE_k<<<gs, 256, 0, stream>>>(proj2, selfE);

    dim3 gc(NTILES, 32);
    convert_kv<<<gc, 256, 0, stream>>>(proj1, Khg, Klg, Vtg);

    attn_rowsum<<<1024, 512, 0, stream>>>(proj1, Khg, selfE, rowinv);

    attn_pv<<<1024, 512, smem_pv, stream>>>(proj1, Khg, Klg, Vtg, selfE, rowinv,
                                            attn, Obuf);

    dim3 g3(mt, 512 / TILE_N);
    gemm_f32<<<g3, 256, 0, stream>>>(Obuf, w_out, out, b_out, MROWS, 512, 512);
}

// Round 4
// 681.197 us; speedup vs baseline: 4.4051x; 1.5931x over previous
//
#include <hip/hip_runtime.h>
#include <hip/hip_bf16.h>

// ---------------------------------------------------------------------------
// AgentAwareAttention (MI355X / gfx950) — Round 4
//   B=4, N=2009, DIM=512, H=8, Dh=64. Out: out [4,2009,512] ++ attn [4,8,2009,2009]
// All GEMMs via split-bf16 (hi/lo, 3-MFMA) emulation; attention MFMA with
// nontemporal attn stores; fragment-major bf16 intermediates everywhere.
// Pipeline:
//   convert_x   : x -> xh/xl (frag-major, M padded to 8192)
//   convert_w   : w_qkv/w_qk_self/w_out -> hi/lo frag-major
//   gemm_bf16<1>: Qf|Kf|Vf = x @ w_qkv      (f32, split matrices [8036x512])
//   gemm_bf16<0>: proj2    = x @ w_qk_self  (f32 [8036x1024])
//   selfE_k     : 10x10 diag-block self-attn exp values
//   convert_kv  : Kf,Vf -> Khg/Klg (hi/lo frag) + Vtg (V^T frag)  [overlays proj2]
//   attn_rowsum : hi-only QK MFMA -> rowinv
//   attn_pv     : split-bf16 QK -> p=e*rinv -> attn (nt stores), PV MFMA ->
//                 Ohg/Olg (bf16 hi/lo frag-major, overlays Kf)
//   gemm_bf16<2>: out = O @ w_out + b_out
// ---------------------------------------------------------------------------

#define N_TOK   2009
#define NPAD    2048
#define NTILES  16
#define BATCH_  4
#define HEADS_  8
#define MROWS   8036
#define SCALE_  0.125f

typedef __attribute__((ext_vector_type(8)))  short sh8;     // 8 bf16
typedef __attribute__((ext_vector_type(16))) float f32x16;  // mfma 32x32 acc

static inline int cdiv(int a, int b) { return (a + b - 1) / b; }

__device__ __forceinline__ float4 ld4(const float* p) {
    return *reinterpret_cast<const float4*>(p);
}
__device__ __forceinline__ unsigned short f2bf(float f) {
    __hip_bfloat16 h = __float2bfloat16(f);
    return *reinterpret_cast<unsigned short*>(&h);
}
__device__ __forceinline__ float bf2f(unsigned short u) {
    return __uint_as_float(((unsigned)u) << 16);
}
__device__ __forceinline__ void cvt8(const float4& a, const float4& b, sh8& hi, sh8& lo) {
    float f[8] = {a.x, a.y, a.z, a.w, b.x, b.y, b.z, b.w};
#pragma unroll
    for (int i = 0; i < 8; ++i) {
        unsigned short h = f2bf(f[i]);
        hi[i] = (short)h;
        lo[i] = (short)f2bf(f[i] - bf2f(h));
    }
}
__device__ __forceinline__ void cvt8p(const float4& a, const float4& b, sh8& hi) {
#pragma unroll
    for (int i = 0; i < 4; ++i) {
        hi[i]     = (short)f2bf((&a.x)[i]);
        hi[4 + i] = (short)f2bf((&b.x)[i]);
    }
}
typedef const __attribute__((address_space(1))) void gas_void;
typedef __attribute__((address_space(3))) void las_void;
__device__ __forceinline__ void gll16(const void* g, void* l) {
    __builtin_amdgcn_global_load_lds((gas_void*)g, (las_void*)l, 16, 0, 0);
}

// ---------------------------------------------------------------------------
// convert_x: x [4,2009,512] f32 -> xh/xl frag-major [mt 64][kc 64][row 128]x8
// (rows padded per batch to 2048)
// ---------------------------------------------------------------------------
__global__ __launch_bounds__(256)
void convert_x(const float* __restrict__ x, unsigned short* __restrict__ xh,
               unsigned short* __restrict__ xl)
{
    const int mt = blockIdx.x;           // 0..63
    const int w  = threadIdx.x >> 6;     // 0..3
    const int kc = threadIdx.x & 63;     // k/8
    for (int it = 0; it < 8; ++it) {
        int rg = it * 4 + w;             // rowgroup 0..31
        sh8 hi[4], lo[4];
#pragma unroll
        for (int rr = 0; rr < 4; ++rr) {
            int row = rg * 4 + rr;
            int gm = mt * 128 + row;
            int b = gm >> 11, gr = gm & 2047;
            float4 a = make_float4(0.f, 0.f, 0.f, 0.f), c = a;
            if (gr < N_TOK) {
                const float* p = x + ((size_t)b * N_TOK + gr) * 512 + kc * 8;
                a = ld4(p); c = ld4(p + 4);
            }
            cvt8(a, c, hi[rr], lo[rr]);
        }
        size_t base = ((size_t)(mt * 64 + kc) * 128 + rg * 4) * 8;
#pragma unroll
        for (int rr = 0; rr < 4; ++rr) {
            *reinterpret_cast<sh8*>(xh + base + rr * 8) = hi[rr];
            *reinterpret_cast<sh8*>(xl + base + rr * 8) = lo[rr];
        }
    }
}

// ---------------------------------------------------------------------------
// convert_w: weights [512, N] -> hi/lo frag-major [nt][kc 64][col 128]x8
// (chunk = 8 consecutive k for fixed col)
// ---------------------------------------------------------------------------
__global__ __launch_bounds__(256)
void convert_w(const float* __restrict__ wqkv, const float* __restrict__ wself,
               const float* __restrict__ wout,
               unsigned short* __restrict__ qh, unsigned short* __restrict__ ql,
               unsigned short* __restrict__ sh, unsigned short* __restrict__ sl,
               unsigned short* __restrict__ oh, unsigned short* __restrict__ ol)
{
    int cid = blockIdx.x * 256 + threadIdx.x;
    int nt_all = cid >> 13, rem = cid & 8191;
    int kc = rem >> 7, col = rem & 127;
    const float* src; unsigned short *dh, *dl; int Nn, ntl;
    if (nt_all < 12)      { src = wqkv;  dh = qh; dl = ql; Nn = 1536; ntl = nt_all; }
    else if (nt_all < 20) { src = wself; dh = sh; dl = sl; Nn = 1024; ntl = nt_all - 12; }
    else                  { src = wout;  dh = oh; dl = ol; Nn = 512;  ntl = nt_all - 20; }
    float f[8];
#pragma unroll
    for (int i = 0; i < 8; ++i)
        f[i] = src[(size_t)(kc * 8 + i) * Nn + ntl * 128 + col];
    sh8 hi, lo;
    cvt8(make_float4(f[0], f[1], f[2], f[3]), make_float4(f[4], f[5], f[6], f[7]), hi, lo);
    size_t off = ((size_t)(ntl * 64 + kc) * 128 + col) * 8;
    *reinterpret_cast<sh8*>(dh + off) = hi;
    *reinterpret_cast<sh8*>(dl + off) = lo;
}

// ---------------------------------------------------------------------------
// split-bf16 MFMA GEMM: C[8192pad x N] = A * B, K=512. BM=BN=128, BK=32 dbuf.
// MODE 0: C=proj2 (Nc=1024); MODE 1: C=Qf|Kf|Vf split; MODE 2: C=out (+bias)
// ---------------------------------------------------------------------------
template<int MODE>
__global__ __launch_bounds__(512)
void gemm_bf16(const unsigned short* __restrict__ Ah, const unsigned short* __restrict__ Al,
               const unsigned short* __restrict__ Bh, const unsigned short* __restrict__ Bl,
               float* __restrict__ C, const float* __restrict__ bias)
{
    __shared__ __align__(16) unsigned short AhS[2][4096], AlS[2][4096],
                                            BhS[2][4096], BlS[2][4096];
    const int tid = threadIdx.x, lane = tid & 63, wid = tid >> 6;
    const int mt = blockIdx.x, ntile = blockIdx.y;
    const int wm = wid >> 2, wn = wid & 3;
    const int lj = lane & 31, g = lane >> 5;

    const unsigned short* Asrc_h = Ah + (size_t)mt * 65536;
    const unsigned short* Asrc_l = Al + (size_t)mt * 65536;
    const unsigned short* Bsrc_h = Bh + (size_t)ntile * 65536;
    const unsigned short* Bsrc_l = Bl + (size_t)ntile * 65536;

#define GSTAGE(BUF, S) do {                                                      \
    gll16(Asrc_h + (size_t)(S) * 4096 + tid * 8, (char*)AhS[BUF] + tid * 16);    \
    gll16(Asrc_l + (size_t)(S) * 4096 + tid * 8, (char*)AlS[BUF] + tid * 16);    \
    gll16(Bsrc_h + (size_t)(S) * 4096 + tid * 8, (char*)BhS[BUF] + tid * 16);    \
    gll16(Bsrc_l + (size_t)(S) * 4096 + tid * 8, (char*)BlS[BUF] + tid * 16);    \
} while (0)

    f32x16 acc[2];
#pragma unroll
    for (int i = 0; i < 16; ++i) { acc[0][i] = 0.f; acc[1][i] = 0.f; }

    GSTAGE(0, 0);
    for (int s = 0; s < 16; ++s) {
        const int buf = s & 1;
        __syncthreads();                       // buf staged (vmcnt drained)
        if (s + 1 < 16) GSTAGE(buf ^ 1, s + 1);  // overlaps compute
#pragma unroll
        for (int ks = 0; ks < 2; ++ks) {
            const int kcl = 2 * ks + g;
            sh8 bh = *reinterpret_cast<const sh8*>(BhS[buf] + (kcl * 128 + wn * 32 + lj) * 8);
            sh8 bl = *reinterpret_cast<const sh8*>(BlS[buf] + (kcl * 128 + wn * 32 + lj) * 8);
#pragma unroll
            for (int Mt = 0; Mt < 2; ++Mt) {
                sh8 ah = *reinterpret_cast<const sh8*>(AhS[buf] + (kcl * 128 + wm * 64 + Mt * 32 + lj) * 8);
                sh8 al = *reinterpret_cast<const sh8*>(AlS[buf] + (kcl * 128 + wm * 64 + Mt * 32 + lj) * 8);
                acc[Mt] = __builtin_amdgcn_mfma_f32_32x32x16_bf16(ah, bh, acc[Mt], 0, 0, 0);
                acc[Mt] = __builtin_amdgcn_mfma_f32_32x32x16_bf16(ah, bl, acc[Mt], 0, 0, 0);
                acc[Mt] = __builtin_amdgcn_mfma_f32_32x32x16_bf16(al, bh, acc[Mt], 0, 0, 0);
            }
        }
    }
#undef GSTAGE

#pragma unroll
    for (int Mt = 0; Mt < 2; ++Mt) {
#pragma unroll
        for (int reg = 0; reg < 16; ++reg) {
            int rloc = wm * 64 + Mt * 32 + (reg & 3) + 8 * (reg >> 2) + 4 * g;
            int gm = mt * 128 + rloc;
            int b = gm >> 11, gr = gm & 2047;
            if (gr < N_TOK) {
                int coln = ntile * 128 + wn * 32 + lj;
                float v = acc[Mt][reg];
                size_t idx;
                if (MODE == 1)
                    idx = ((size_t)(coln >> 9) * MROWS + (size_t)b * N_TOK + gr) * 512 + (coln & 511);
                else if (MODE == 0)
                    idx = ((size_t)b * N_TOK + gr) * 1024 + coln;
                else {
                    v += bias[coln];
                    idx = ((size_t)b * N_TOK + gr) * 512 + coln;
                }
                C[idx] = v;
            }
        }
    }
}

// ---------------------------------------------------------------------------
// selfE: per (bh, agent a): 10x10 exp(scale * qs_r . ks_j)
// ---------------------------------------------------------------------------
__global__ __launch_bounds__(256)
void selfE_k(const float* __restrict__ proj2, float* __restrict__ selfE)
{
    __shared__ float qs[10][64];
    __shared__ float ks[10][68];
    const int a = blockIdx.x;
    const int h = blockIdx.y & 7;
    const int b = blockIdx.y >> 3;
    const size_t rowbase = (size_t)b * N_TOK + a * 10;

    for (int i = threadIdx.x; i < 320; i += 256) {
        int r = i >> 4;
        int c = (i & 15) * 4;
        const float* src = proj2 + (rowbase + (r % 10)) * 1024
                         + (r < 10 ? 0 : 512) + h * 64 + c;
        float4 v = ld4(src);
        if (r < 10) *reinterpret_cast<float4*>(&qs[r][c]) = v;
        else        *reinterpret_cast<float4*>(&ks[r - 10][c]) = v;
    }
    __syncthreads();
    if (threadIdx.x < 100) {
        int r = threadIdx.x / 10, c = threadIdx.x % 10;
        float acc = 0.f;
#pragma unroll 8
        for (int d = 0; d < 64; ++d) acc += qs[r][d] * ks[c][d];
        int bh = b * HEADS_ + h;
        selfE[((size_t)bh * 2000 + a * 10 + r) * 10 + c] = __expf(acc * SCALE_);
    }
}

// ---------------------------------------------------------------------------
// convert K -> Khg/Klg (hi/lo, [bh][t][kc 8][row 128]x8), V -> Vtg
// ([bh][t][jc 16][d 64]x8)
// ---------------------------------------------------------------------------
__global__ __launch_bounds__(256)
void convert_kv(const float* __restrict__ Kf, const float* __restrict__ Vf,
                unsigned short* __restrict__ Khg, unsigned short* __restrict__ Klg,
                unsigned short* __restrict__ Vtg)
{
    __shared__ float vtile[128][66];
    const int t  = blockIdx.x;
    const int h  = blockIdx.y & 7;
    const int b  = blockIdx.y >> 3;
    const int bh = blockIdx.y;
    const size_t bN = (size_t)b * N_TOK;
    const size_t tbase = ((size_t)bh * NTILES + t) * 8192;
    const int tid = threadIdx.x;

    {
        int r = tid >> 1, q = tid & 1;
        int gj = t * 128 + r;
        float4 f[8];
        if (gj < N_TOK) {
            const float* kp = Kf + (bN + gj) * 512 + h * 64 + q * 32;
#pragma unroll
            for (int i = 0; i < 8; ++i) f[i] = ld4(kp + 4 * i);
        } else {
#pragma unroll
            for (int i = 0; i < 8; ++i) f[i] = make_float4(0.f, 0.f, 0.f, 0.f);
        }
#pragma unroll
        for (int cp = 0; cp < 4; ++cp) {
            sh8 hi, lo;
            cvt8(f[2 * cp], f[2 * cp + 1], hi, lo);
            int kc = q * 4 + cp;
            size_t off = tbase + ((size_t)kc * 128 + r) * 8;
            *reinterpret_cast<sh8*>(Khg + off) = hi;
            *reinterpret_cast<sh8*>(Klg + off) = lo;
        }
    }
    {
        int r = tid >> 1, q = tid & 1;
        int gj = t * 128 + r;
        const float* vp = Vf + (bN + gj) * 512 + h * 64 + q * 32;
#pragma unroll
        for (int i = 0; i < 8; ++i) {
            float4 v = (gj < N_TOK) ? ld4(vp + 4 * i) : make_float4(0.f, 0.f, 0.f, 0.f);
            *reinterpret_cast<float4*>(&vtile[r][q * 32 + 4 * i]) = v;
        }
    }
    __syncthreads();
    {
        int d = tid & 63, jg = tid >> 6;
#pragma unroll
        for (int jj = 0; jj < 4; ++jj) {
            int jc = jg * 4 + jj;
            sh8 pk;
#pragma unroll
            for (int i = 0; i < 8; ++i) pk[i] = (short)f2bf(vtile[jc * 8 + i][d]);
            *reinterpret_cast<sh8*>(Vtg + tbase + ((size_t)jc * 64 + d) * 8) = pk;
        }
    }
}

// ---------------------------------------------------------------------------
// pass A: rowsums (hi-only QK) -> rowinv
// ---------------------------------------------------------------------------
__global__ __launch_bounds__(512, 4)
void attn_rowsum(const float* __restrict__ Qf,
                 const unsigned short* __restrict__ Khg,
                 const float* __restrict__ selfE,
                 float* __restrict__ rowinv)
{
    __shared__ __align__(16) unsigned short KhS[8192];
    __shared__ float selfS[640];
    __shared__ float partial[256];

    const int w  = ((blockIdx.x & 7) << 7) | (blockIdx.x >> 3);
    const int bx = w & 31;
    const int bh = w >> 5;
    const int h  = bh & 7, b = bh >> 3;
    const int tid = threadIdx.x, lane = tid & 63, wid = tid >> 6;
    const int row0 = bx * 64;
    const size_t bN = (size_t)b * N_TOK;

    for (int i = tid; i < 640; i += 512) {
        int r = i / 10, c = i - r * 10;
        int gr = row0 + r;
        selfS[i] = (gr < 2000) ? selfE[((size_t)bh * 2000 + gr) * 10 + c] : 0.f;
    }
    {
        int r = lane, q = wid;
        int gr = row0 + r;
        float4 a = make_float4(0.f, 0.f, 0.f, 0.f), b4 = a;
        if (gr < N_TOK) {
            const float* qp = Qf + (bN + gr) * 512 + h * 64 + q * 8;
            a = ld4(qp); b4 = ld4(qp + 4);
        }
        sh8 hi; cvt8p(a, b4, hi);
        *reinterpret_cast<sh8*>(KhS + ((size_t)q * 64 + r) * 8) = hi;
    }
    __syncthreads();

    const int rt = wid & 1, ct = wid >> 1;
    const int lj = lane & 31, g = lane >> 5;
    sh8 qh[4];
#pragma unroll
    for (int ks = 0; ks < 4; ++ks)
        qh[ks] = *reinterpret_cast<const sh8*>(KhS + ((2 * ks + g) * 64 + 32 * rt + lj) * 8);
    __syncthreads();

    const unsigned short* ktiles = Khg + (size_t)bh * NTILES * 8192;
#pragma unroll
    for (int i = 0; i < 2; ++i)
        gll16(ktiles + i * 4096 + wid * 512 + lane * 8,
              (char*)KhS + i * 8192 + wid * 1024 + lane * 16);

    float rsacc[16];
#pragma unroll
    for (int i = 0; i < 16; ++i) rsacc[i] = 0.f;

    const int alo = (row0 / 10) * 10;
    const int rmax = row0 + 63 < 1999 ? row0 + 63 : 1999;
    const int ahi = (rmax / 10) * 10 + 10;

    for (int t = 0; t < NTILES; ++t) {
        __syncthreads();
        sh8 kf[4];
#pragma unroll
        for (int ks = 0; ks < 4; ++ks)
            kf[ks] = *reinterpret_cast<const sh8*>(KhS + ((2 * ks + g) * 128 + 32 * ct + lj) * 8);
        f32x16 s;
#pragma unroll
        for (int i = 0; i < 16; ++i) s[i] = 0.f;
#pragma unroll
        for (int ks = 0; ks < 4; ++ks)
            s = __builtin_amdgcn_mfma_f32_32x32x16_bf16(qh[ks], kf[ks], s, 0, 0, 0);
        __syncthreads();
        if (t + 1 < NTILES) {
            const unsigned short* kt = ktiles + (size_t)(t + 1) * 8192;
#pragma unroll
            for (int i = 0; i < 2; ++i)
                gll16(kt + i * 4096 + wid * 512 + lane * 8,
                      (char*)KhS + i * 8192 + wid * 1024 + lane * 16);
        }
        const int cin = 32 * ct + lj;
        const int gj  = t * 128 + cin;
        if (gj < N_TOK) {
            const bool dtile = (alo < t * 128 + 128) && (ahi > t * 128);
#pragma unroll
            for (int reg = 0; reg < 16; ++reg) {
                int rowr = 32 * rt + (reg & 3) + 8 * (reg >> 2) + 4 * g;
                int gr = row0 + rowr;
                float e = __expf(s[reg] * SCALE_);
                if (dtile && gr < 2000) {
                    int a0 = (gr / 10) * 10;
                    unsigned cc = (unsigned)(gj - a0);
                    if (cc < 10u) e = selfS[rowr * 10 + (int)cc];
                }
                rsacc[reg] += e;
            }
        }
    }

#pragma unroll
    for (int reg = 0; reg < 16; ++reg) {
        float v = rsacc[reg];
        v += __shfl_xor(v, 1);  v += __shfl_xor(v, 2);
        v += __shfl_xor(v, 4);  v += __shfl_xor(v, 8);
        v += __shfl_xor(v, 16);
        rsacc[reg] = v;
    }
    if (lj == 0) {
#pragma unroll
        for (int reg = 0; reg < 16; ++reg) {
            int rowr = 32 * rt + (reg & 3) + 8 * (reg >> 2) + 4 * g;
            partial[ct * 64 + rowr] = rsacc[reg];
        }
    }
    __syncthreads();
    if (tid < 64) {
        float ssum = partial[tid] + partial[64 + tid] + partial[128 + tid] + partial[192 + tid];
        int gr = row0 + tid;
        rowinv[(size_t)bh * NPAD + row0 + tid] = (gr < N_TOK) ? 1.0f / ssum : 0.f;
    }
}

// ---------------------------------------------------------------------------
// pass B: split-bf16 QK -> p = e*rinv -> attn (nt stores); PV -> Ohg/Olg
// ---------------------------------------------------------------------------
__global__ __launch_bounds__(512, 4)
void attn_pv(const float* __restrict__ Qf,
             const unsigned short* __restrict__ Khg,
             const unsigned short* __restrict__ Klg,
             const unsigned short* __restrict__ Vtg,
             const float* __restrict__ selfE,
             const float* __restrict__ rowinv,
             float* __restrict__ attn,
             unsigned short* __restrict__ Ohg, unsigned short* __restrict__ Olg)
{
    extern __shared__ __align__(16) char smem[];
    unsigned short* KhS = (unsigned short*)smem;    // 8192 halfs
    unsigned short* KlS = KhS + 8192;
    unsigned short* VtS = KlS + 8192;
    unsigned short* psS = VtS + 8192;
    float* selfS = (float*)(psS + 8192);            // 640
    float* rinvS = selfS + 640;                     // 64

    const int w  = ((blockIdx.x & 7) << 7) | (blockIdx.x >> 3);
    const int bx = w & 31;
    const int bh = w >> 5;
    const int h  = bh & 7, b = bh >> 3;
    const int tid = threadIdx.x, lane = tid & 63, wid = tid >> 6;
    const int row0 = bx * 64;
    const size_t bN = (size_t)b * N_TOK;
    const size_t abase = ((size_t)bh * N_TOK + row0) * N_TOK;

    for (int i = tid; i < 640; i += 512) {
        int r = i / 10, c = i - r * 10;
        int gr = row0 + r;
        selfS[i] = (gr < 2000) ? selfE[((size_t)bh * 2000 + gr) * 10 + c] : 0.f;
    }
    if (tid < 64) rinvS[tid] = rowinv[(size_t)bh * NPAD + row0 + tid];

    {
        int r = lane, q = wid;
        int gr = row0 + r;
        float4 a = make_float4(0.f, 0.f, 0.f, 0.f), b4 = a;
        if (gr < N_TOK) {
            const float* qp = Qf + (bN + gr) * 512 + h * 64 + q * 8;
            a = ld4(qp); b4 = ld4(qp + 4);
        }
        sh8 hi, lo; cvt8(a, b4, hi, lo);
        *reinterpret_cast<sh8*>(KhS + ((size_t)q * 64 + r) * 8) = hi;
        *reinterpret_cast<sh8*>(KlS + ((size_t)q * 64 + r) * 8) = lo;
    }
    __syncthreads();

    const int rt = wid & 1, ct = wid >> 1;
    const int dt = (wid >> 1) & 1, kh = wid >> 2;
    const int lj = lane & 31, g = lane >> 5;
    sh8 qh[4], ql[4];
#pragma unroll
    for (int ks = 0; ks < 4; ++ks) {
        qh[ks] = *reinterpret_cast<const sh8*>(KhS + ((2 * ks + g) * 64 + 32 * rt + lj) * 8);
        ql[ks] = *reinterpret_cast<const sh8*>(KlS + ((2 * ks + g) * 64 + 32 * rt + lj) * 8);
    }
    __syncthreads();

    const unsigned short* khT = Khg + (size_t)bh * NTILES * 8192;
    const unsigned short* klT = Klg + (size_t)bh * NTILES * 8192;
    const unsigned short* vtT = Vtg + (size_t)bh * NTILES * 8192;

#define STAGE_K(T) do { size_t tb = (size_t)(T) * 8192;                                  \
    _Pragma("unroll") for (int i = 0; i < 2; ++i) {                                      \
        gll16(khT + tb + i * 4096 + wid * 512 + lane * 8,                                \
              (char*)KhS + i * 8192 + wid * 1024 + lane * 16);                           \
        gll16(klT + tb + i * 4096 + wid * 512 + lane * 8,                                \
              (char*)KlS + i * 8192 + wid * 1024 + lane * 16); } } while (0)
#define STAGE_V(T) do { size_t tb = (size_t)(T) * 8192;                                  \
    _Pragma("unroll") for (int i = 0; i < 2; ++i)                                        \
        gll16(vtT + tb + i * 4096 + wid * 512 + lane * 8,                                \
              (char*)VtS + i * 8192 + wid * 1024 + lane * 16); } while (0)

    STAGE_K(0);
    STAGE_V(0);

    const int alo = (row0 / 10) * 10;
    const int rmax = row0 + 63 < 1999 ? row0 + 63 : 1999;
    const int ahi = (rmax / 10) * 10 + 10;

    f32x16 oacc;
#pragma unroll
    for (int i = 0; i < 16; ++i) oacc[i] = 0.f;

    for (int t = 0; t < NTILES; ++t) {
        __syncthreads();                       // B0: staging complete
        sh8 kfh[4], kfl[4];
#pragma unroll
        for (int ks = 0; ks < 4; ++ks) {
            kfh[ks] = *reinterpret_cast<const sh8*>(KhS + ((2 * ks + g) * 128 + 32 * ct + lj) * 8);
            kfl[ks] = *reinterpret_cast<const sh8*>(KlS + ((2 * ks + g) * 128 + 32 * ct + lj) * 8);
        }
        f32x16 s;
#pragma unroll
        for (int i = 0; i < 16; ++i) s[i] = 0.f;
#pragma unroll
        for (int ks = 0; ks < 4; ++ks) {
            s = __builtin_amdgcn_mfma_f32_32x32x16_bf16(qh[ks], kfh[ks], s, 0, 0, 0);
            s = __builtin_amdgcn_mfma_f32_32x32x16_bf16(qh[ks], kfl[ks], s, 0, 0, 0);
            s = __builtin_amdgcn_mfma_f32_32x32x16_bf16(ql[ks], kfh[ks], s, 0, 0, 0);
        }
        const int cin = 32 * ct + lj;
        const int gj  = t * 128 + cin;
        const bool jv = gj < N_TOK;
        const bool dtile = (alo < t * 128 + 128) && (ahi > t * 128);
        float* ap = attn + abase + gj;
#pragma unroll
        for (int reg = 0; reg < 16; ++reg) {
            int rowr = 32 * rt + (reg & 3) + 8 * (reg >> 2) + 4 * g;
            int gr = row0 + rowr;
            float e = 0.f;
            if (jv && gr < N_TOK) e = __expf(s[reg] * SCALE_);
            if (dtile && jv && gr < 2000) {
                int a0 = (gr / 10) * 10;
                unsigned cc = (unsigned)(gj - a0);
                if (cc < 10u) e = selfS[rowr * 10 + (int)cc];
            }
            float p = e * rinvS[rowr];
            if (jv && gr < N_TOK)
                __builtin_nontemporal_store(p, ap + (size_t)rowr * N_TOK);
            int jcw = 4 * ct + (lj >> 3);
            psS[((size_t)jcw * 64 + (rowr ^ (jcw & 7))) * 8 + (lj & 7)] = f2bf(p);
        }
        __syncthreads();                       // B2: K reads done + ps visible
        if (t + 1 < NTILES) STAGE_K(t + 1);    // overlaps PV
#pragma unroll
        for (int ks = 0; ks < 4; ++ks) {
            int jc = 8 * kh + 2 * ks + g;
            sh8 pa = *reinterpret_cast<const sh8*>(
                psS + ((size_t)jc * 64 + ((32 * rt + lj) ^ (jc & 7))) * 8);
            sh8 vf = *reinterpret_cast<const sh8*>(VtS + ((size_t)jc * 64 + 32 * dt + lj) * 8);
            oacc = __builtin_amdgcn_mfma_f32_32x32x16_bf16(pa, vf, oacc, 0, 0, 0);
        }
        __syncthreads();                       // B3: V/ps reads done
        if (t + 1 < NTILES) STAGE_V(t + 1);
    }
#undef STAGE_K
#undef STAGE_V

    // ---- epilogue: merge kh halves, emit O as bf16 hi/lo fragments ----
    float* Opart = (float*)smem;               // [64][68]
    float* Ofull = Opart + 64 * 68;            // [64][68]
    if (kh == 1) {
#pragma unroll
        for (int reg = 0; reg < 16; ++reg) {
            int rowl = (reg & 3) + 8 * (reg >> 2) + 4 * g;
            Opart[(32 * rt + rowl) * 68 + 32 * dt + lj] = oacc[reg];
        }
    }
    __syncthreads();
    if (kh == 0) {
#pragma unroll
        for (int reg = 0; reg < 16; ++reg) {
            int rowl = (reg & 3) + 8 * (reg >> 2) + 4 * g;
            int rloc = 32 * rt + rowl;
            Ofull[rloc * 68 + 32 * dt + lj] = oacc[reg] + Opart[rloc * 68 + 32 * dt + lj];
        }
    }
    __syncthreads();
    {
        int row = tid >> 3, kq = tid & 7;
        const float* op = Ofull + row * 68 + kq * 8;
        float4 a = ld4(op), c = ld4(op + 4);
        sh8 hi, lo; cvt8(a, c, hi, lo);
        int mtile = (b * 32 + bx) >> 1;
        int row128 = ((bx & 1) << 6) + row;
        size_t off = ((size_t)(mtile * 64 + h * 8 + kq) * 128 + row128) * 8;
        *reinterpret_cast<sh8*>(Ohg + off) = hi;
        *reinterpret_cast<sh8*>(Olg + off) = lo;
    }
}

// ---------------------------------------------------------------------------
extern "C" void kernel_launch(void* const* d_in, const int* in_sizes, int n_in,
                              void* d_out, int out_size, void* d_ws, size_t ws_size,
                              hipStream_t stream)
{
    const float* x         = (const float*)d_in[0];
    const float* w_qkv     = (const float*)d_in[1];
    const float* w_qk_self = (const float*)d_in[2];
    const float* w_out     = (const float*)d_in[3];
    const float* b_out     = (const float*)d_in[4];

    float* out  = (float*)d_out;                       // [8036,512]
    float* attn = out + (size_t)MROWS * 512;           // [4,8,2009,2009]

    // ---- workspace layout ----
    float* Qf = (float*)d_ws;                          // 8036*512 f32
    float* Kf = Qf + (size_t)MROWS * 512;
    float* Vf = Kf + (size_t)MROWS * 512;
    float* p2 = Vf + (size_t)MROWS * 512;              // proj2 [8036*1024] f32
    unsigned short* Khg = (unsigned short*)p2;         // then Khg/Klg/Vtg (24MB)
    unsigned short* Klg = Khg + 4194304;
    unsigned short* Vtg = Klg + 4194304;
    float* proj2 = p2;
    float* after_p2 = p2 + (size_t)MROWS * 1024;
    unsigned short* xh  = (unsigned short*)after_p2;   // 8192*512 halfs
    unsigned short* xl  = xh + 4194304;
    unsigned short* Wqh = xl + 4194304;                // 512*1536
    unsigned short* Wql = Wqh + 786432;
    unsigned short* Wsh = Wql + 786432;                // 512*1024
    unsigned short* Wsl = Wsh + 524288;
    unsigned short* Woh = Wsl + 524288;                // 512*512
    unsigned short* Wol = Woh + 262144;
    float* rowinv = (float*)(Wol + 262144);            // 32*2048
    float* selfE  = rowinv + 65536;                    // 32*2000*10
    // Ohg/Olg overlay Kf (+ start of Vf), both dead after convert_kv:
    unsigned short* Ohg = (unsigned short*)Kf;         // 8192*512 halfs
    unsigned short* Olg = Ohg + 4194304;
    // total ws usage ≈ 108.2 MB

    const int smem_pv = 4 * 8192 * 2 + 640 * 4 + 64 * 4;   // 68,352 B
    hipFuncSetAttribute((const void*)attn_pv,
                        hipFuncAttributeMaxDynamicSharedMemorySize, smem_pv);

    convert_x<<<64, 256, 0, stream>>>(x, xh, xl);
    convert_w<<<768, 256, 0, stream>>>(w_qkv, w_qk_self, w_out,
                                       Wqh, Wql, Wsh, Wsl, Woh, Wol);

    dim3 g1(64, 12);
    gemm_bf16<1><<<g1, 512, 0, stream>>>(xh, xl, Wqh, Wql, Qf, nullptr);

    dim3 g2(64, 8);
    gemm_bf16<0><<<g2, 512, 0, stream>>>(xh, xl, Wsh, Wsl, proj2, nullptr);

    dim3 gs(200, 32);
    selfE_k<<<gs, 256, 0, stream>>>(proj2, selfE);

    dim3 gc(NTILES, 32);
    convert_kv<<<gc, 256, 0, stream>>>(Kf, Vf, Khg, Klg, Vtg);

    attn_rowsum<<<1024, 512, 0, stream>>>(Qf, Khg, selfE, rowinv);

    attn_pv<<<1024, 512, smem_pv, stream>>>(Qf, Khg, Klg, Vtg, selfE, rowinv,
                                            attn, Ohg, Olg);

    dim3 g3(64, 4);
    gemm_bf16<2><<<g3, 512, 0, stream>>>(Ohg, Olg, Woh, Wol, out, b_out);
}